// Round 1
// baseline (419.967 us; speedup 1.0000x reference)
//
#include <hip/hip_runtime.h>

// STN bilinear sampler: x [32,256,256,32] f32 NHWC, theta [32,6] f32
// out [32,256,256,32] f32.
// Coordinate math in fp64 to replicate the numpy (ref=np) reference exactly:
// np.linspace(-1,1,256) is float64 and promotes the whole coord chain.
// Truncation (int cast) boundaries must match or we get O(1) index-flip errors.

#define B_  32
#define H_  256
#define W_  256
#define C_  32
#define P_  (H_ * W_)   // 65536 output pixels per batch

__global__ __launch_bounds__(256) void stn_kernel(
    const float* __restrict__ x,
    const float* __restrict__ theta,
    float* __restrict__ out)
{
    __shared__ double t[6];

    const long long gid = (long long)blockIdx.x * 256 + threadIdx.x;
    const int p   = (int)(gid >> 3);   // global output pixel index
    const int v   = (int)(gid & 7);    // which float4 of the 32 channels
    const int b   = p >> 16;           // p / 65536
    const int rem = p & 65535;
    const int py  = rem >> 8;
    const int px  = rem & 255;

    // theta row is uniform across the block (a block spans 32 consecutive
    // pixels of one image). Stage in LDS as double.
    if (threadIdx.x < 6) t[threadIdx.x] = (double)theta[b * 6 + threadIdx.x];
    __syncthreads();

    // numpy: xs[i] = (2.0*i)/255.0 - 1.0  (exact at i=255 -> 1.0)
    const double gx = (2.0 * (double)px) / 255.0 - 1.0;
    const double gy = (2.0 * (double)py) / 255.0 - 1.0;

    // einsum order: (t0*gx + t1*gy) + t2
    const double sxs = t[0] * gx + t[1] * gy + t[2];
    const double sys = t[3] * gx + t[4] * gy + t[5];

    // sx = 0.5*(s+1.0)*W
    const double sx = 0.5 * (sxs + 1.0) * (double)W_;
    const double sy = 0.5 * (sys + 1.0) * (double)H_;

    // truncation toward zero, matching astype(int32)
    const int x0 = (int)sx;
    const int y0 = (int)sy;
    const int x1 = x0 + 1;
    const int y1 = y0 + 1;

    const int x0c = min(max(x0, 0), W_ - 1);
    const int x1c = min(max(x1, 0), W_ - 1);
    const int y0c = min(max(y0, 0), H_ - 1);
    const int y1c = min(max(y1, 0), H_ - 1);

    const double x0f = (double)x0c, x1f = (double)x1c;
    const double y0f = (double)y0c, y1f = (double)y1c;

    const float wa = (float)((x1f - sx) * (y1f - sy));
    const float wb = (float)((x1f - sx) * (sy - y0f));
    const float wc = (float)((sx - x0f) * (y1f - sy));
    const float wd = (float)((sx - x0f) * (sy - y0f));

    const long long base = (long long)b * (H_ * W_);
    const long long ia = (base + (long long)(y0c * W_ + x0c)) * C_ + v * 4;
    const long long ib = (base + (long long)(y1c * W_ + x0c)) * C_ + v * 4;
    const long long ic = (base + (long long)(y0c * W_ + x1c)) * C_ + v * 4;
    const long long id = (base + (long long)(y1c * W_ + x1c)) * C_ + v * 4;

    const float4 pa = *reinterpret_cast<const float4*>(x + ia);
    const float4 pb = *reinterpret_cast<const float4*>(x + ib);
    const float4 pc = *reinterpret_cast<const float4*>(x + ic);
    const float4 pd = *reinterpret_cast<const float4*>(x + id);

    float4 r;
    r.x = wa * pa.x + wb * pb.x + wc * pc.x + wd * pd.x;
    r.y = wa * pa.y + wb * pb.y + wc * pc.y + wd * pd.y;
    r.z = wa * pa.z + wb * pb.z + wc * pc.z + wd * pd.z;
    r.w = wa * pa.w + wb * pb.w + wc * pc.w + wd * pd.w;

    *reinterpret_cast<float4*>(out + (long long)p * C_ + v * 4) = r;
}

extern "C" void kernel_launch(void* const* d_in, const int* in_sizes, int n_in,
                              void* d_out, int out_size, void* d_ws, size_t ws_size,
                              hipStream_t stream) {
    const float* x     = (const float*)d_in[0];
    const float* theta = (const float*)d_in[1];
    float* out         = (float*)d_out;

    // total threads = B*P*8 = 16,777,216 -> 65536 blocks of 256
    const int total_threads = B_ * P_ * 8;
    const int block = 256;
    const int grid = total_threads / block;  // 65536

    stn_kernel<<<grid, block, 0, stream>>>(x, theta, out);
}

// Round 3
// 413.778 us; speedup vs baseline: 1.0150x; 1.0150x over previous
//
#include <hip/hip_runtime.h>

// STN bilinear sampler: x [32,256,256,32] f32 NHWC, theta [32,6] f32
// out [32,256,256,32] f32.
//
// R1: 420 us with 32x1-pixel blocks -> at/below the zero-reuse roofline
// (4 lines/pixel fetched). R2/R3: 8x4-pixel 2D tiles for L1/L2 tap reuse +
// non-temporal output stores (input is 256 MiB == L3 size; don't pollute).
// R3 fix: __builtin_nontemporal_store needs a clang ext_vector, not HIP float4.
//
// Coordinate math in fp64 to replicate the numpy (ref=np) reference exactly:
// np.linspace(-1,1,256) is float64 and promotes the whole coord chain.
// Truncation (int cast) boundaries must match or we get O(1) index-flips.

#define B_  32
#define H_  256
#define W_  256
#define C_  32

// tile: 8 px in x, 4 px in y; 8 threads per pixel (one float4 of C each)
#define TX_ 8
#define TY_ 4

typedef float floatx4 __attribute__((ext_vector_type(4)));

__global__ __launch_bounds__(256) void stn_kernel(
    const float* __restrict__ x,
    const float* __restrict__ theta,
    float* __restrict__ out)
{
    __shared__ double t[6];

    const int tid = threadIdx.x;
    const int v   = tid & 7;          // channel chunk (v*4 .. v*4+3)
    const int pxl = tid >> 3;         // 0..31 pixel within tile
    const int tx  = pxl & (TX_ - 1);
    const int ty  = pxl >> 3;

    const int px = blockIdx.x * TX_ + tx;
    const int py = blockIdx.y * TY_ + ty;
    const int b  = blockIdx.z;

    if (tid < 6) t[tid] = (double)theta[b * 6 + tid];
    __syncthreads();

    // numpy: xs[i] = (2.0*i)/255.0 - 1.0
    const double gx = (2.0 * (double)px) / 255.0 - 1.0;
    const double gy = (2.0 * (double)py) / 255.0 - 1.0;

    // einsum order: (t0*gx + t1*gy) + t2
    const double sxs = t[0] * gx + t[1] * gy + t[2];
    const double sys = t[3] * gx + t[4] * gy + t[5];

    const double sx = 0.5 * (sxs + 1.0) * (double)W_;
    const double sy = 0.5 * (sys + 1.0) * (double)H_;

    // truncation toward zero, matching astype(int32)
    const int x0 = (int)sx;
    const int y0 = (int)sy;
    const int x1 = x0 + 1;
    const int y1 = y0 + 1;

    const int x0c = min(max(x0, 0), W_ - 1);
    const int x1c = min(max(x1, 0), W_ - 1);
    const int y0c = min(max(y0, 0), H_ - 1);
    const int y1c = min(max(y1, 0), H_ - 1);

    const double x0f = (double)x0c, x1f = (double)x1c;
    const double y0f = (double)y0c, y1f = (double)y1c;

    const float wa = (float)((x1f - sx) * (y1f - sy));
    const float wb = (float)((x1f - sx) * (sy - y0f));
    const float wc = (float)((sx - x0f) * (y1f - sy));
    const float wd = (float)((sx - x0f) * (sy - y0f));

    const long long base = (long long)b * (H_ * W_);
    const long long ia = (base + (long long)(y0c * W_ + x0c)) * C_ + v * 4;
    const long long ib = (base + (long long)(y1c * W_ + x0c)) * C_ + v * 4;
    const long long ic = (base + (long long)(y0c * W_ + x1c)) * C_ + v * 4;
    const long long id = (base + (long long)(y1c * W_ + x1c)) * C_ + v * 4;

    const floatx4 pa = *reinterpret_cast<const floatx4*>(x + ia);
    const floatx4 pb = *reinterpret_cast<const floatx4*>(x + ib);
    const floatx4 pc = *reinterpret_cast<const floatx4*>(x + ic);
    const floatx4 pd = *reinterpret_cast<const floatx4*>(x + id);

    floatx4 r = wa * pa + wb * pb + wc * pc + wd * pd;

    const long long po = (long long)((b << 16) | (py << 8) | px);
    __builtin_nontemporal_store(r,
        reinterpret_cast<floatx4*>(out + po * C_ + v * 4));
}

extern "C" void kernel_launch(void* const* d_in, const int* in_sizes, int n_in,
                              void* d_out, int out_size, void* d_ws, size_t ws_size,
                              hipStream_t stream) {
    const float* x     = (const float*)d_in[0];
    const float* theta = (const float*)d_in[1];
    float* out         = (float*)d_out;

    dim3 grid(W_ / TX_, H_ / TY_, B_);   // 32 x 64 x 32
    dim3 block(256);

    stn_kernel<<<grid, block, 0, stream>>>(x, theta, out);
}